// Round 5
// baseline (2295.572 us; speedup 1.0000x reference)
//
#include <hip/hip_runtime.h>

// RNN: out[n,t,:] = tanh(x[n,t,:]@Wx + b + h_{t-1}@Wh),  h_{-1} = h0
// N=64, T=512, D=512, H=1024, fp32 in/out.
// Round 5: 4 groups x 16 rows x 32 blocks; Wh pinned in VGPRs (asm touch,
// launch_bounds(256,1)); single batched h-load + one vmcnt; per-thread
// coalesced short posts; fast tanh; 16B-strided flags.

#define NN 64
#define TT 512
#define DD 512
#define HH 1024

typedef unsigned int  u32;
typedef unsigned short u16;

typedef __attribute__((ext_vector_type(8))) short bf16x8;
typedef __attribute__((ext_vector_type(4))) float f32x4;
typedef __attribute__((ext_vector_type(4))) u32   u32x4;

#define MFMA16(a, b, c) __builtin_amdgcn_mfma_f32_16x16x32_bf16((a), (b), (c), 0, 0, 0)

__device__ __forceinline__ u32 bf16r(float f) {          // RTNE fp32->bf16 (bits)
    u32 u = __float_as_uint(f);
    return (u + 0x7fffu + ((u >> 16) & 1u)) >> 16;
}
__device__ __forceinline__ float bf16tof(u32 h) { return __uint_as_float(h << 16); }
__device__ __forceinline__ void split2(float f, u32& hi, u32& lo) {
    hi = bf16r(f);
    lo = bf16r(f - bf16tof(hi));
}

// ---- system-scope (sc0 sc1) memory ops: visible at the coherence point ----
__device__ __forceinline__ u32x4 ld16_sys(const u16* p) {   // issue-only
    u32x4 v;
    asm volatile("global_load_dwordx4 %0, %1, off sc0 sc1" : "=v"(v) : "v"(p));
    return v;
}
__device__ __forceinline__ void st2_sys(u16* p, u32 v) {
    asm volatile("global_store_short %0, %1, off sc0 sc1" :: "v"(p), "v"(v) : "memory");
}
__device__ __forceinline__ u32 ld_flag(const u32* p) {
    u32 v;
    asm volatile("global_load_dword %0, %1, off sc0 sc1\n\ts_waitcnt vmcnt(0)"
                 : "=v"(v) : "v"(p) : "memory");
    return v;
}
__device__ __forceinline__ void st_flag(u32* p, u32 v) {
    asm volatile("global_store_dword %0, %1, off sc0 sc1" :: "v"(p), "v"(v) : "memory");
}

__device__ __forceinline__ float fast_tanh(float x) {
    float e = __expf(2.0f * x);                 // v_exp_f32 path
    return 1.0f - __fdividef(2.0f, e + 1.0f);   // exact +/-1 saturation at inf/0
}

// ---------------------------------------------------------------------------
// Prep: pack Wx and Wh into MFMA-fragment order (hi/lo bf16); split h0.
// Fragment layout for 16x16x32: p = ((jt*KB + kb)*64 + lane)*8 + e
//   j = jt*16 + (lane&15),  k = kb*32 + (lane>>4)*8 + e
// ---------------------------------------------------------------------------
__global__ __launch_bounds__(256) void prep_kernel(
    const float* __restrict__ Wx, const float* __restrict__ Wh,
    const float* __restrict__ h0,
    u16* __restrict__ WxPh, u16* __restrict__ WxPl,
    u16* __restrict__ WhPh, u16* __restrict__ WhPl,
    u16* __restrict__ h0H,  u16* __restrict__ h0L)
{
    const int stride = gridDim.x * 256;
    const int gid = blockIdx.x * 256 + threadIdx.x;

    for (int p = gid; p < 64 * 16 * 64 * 8; p += stride) {   // Wx
        int e = p & 7, l = (p >> 3) & 63, kb = (p >> 9) & 15, jt = p >> 13;
        int j = jt * 16 + (l & 15);
        int k = kb * 32 + ((l >> 4) << 3) + e;
        u32 hi, lo; split2(Wx[k * HH + j], hi, lo);
        WxPh[p] = (u16)hi; WxPl[p] = (u16)lo;
    }
    for (int p = gid; p < 64 * 32 * 64 * 8; p += stride) {   // Wh
        int e = p & 7, l = (p >> 3) & 63, kb = (p >> 9) & 31, jt = p >> 14;
        int j = jt * 16 + (l & 15);
        int k = kb * 32 + ((l >> 4) << 3) + e;
        u32 hi, lo; split2(Wh[k * HH + j], hi, lo);
        WhPh[p] = (u16)hi; WhPl[p] = (u16)lo;
    }
    for (int p = gid; p < NN * HH; p += stride) {            // h0 -> parity 0
        u32 hi, lo; split2(h0[p], hi, lo);
        h0H[p] = (u16)hi; h0L[p] = (u16)lo;
    }
}

// ---------------------------------------------------------------------------
// Phase 1: out = x@Wx + b   (split-bf16, 128x128 tiles, grid 2048)
// ---------------------------------------------------------------------------
__global__ __launch_bounds__(256) void gemm_kernel(
    const float* __restrict__ x, const float* __restrict__ b,
    const u16* __restrict__ WxPh, const u16* __restrict__ WxPl,
    float* __restrict__ out)
{
    __shared__ __align__(16) u32 ldsA[2][128][20];

    const int tid = threadIdx.x;
    const int bid = blockIdx.x;
    const int w   = tid >> 6;
    const int l   = tid & 63;
    const int wm = w >> 1, wj = w & 1;

    const int m0 = (bid >> 3) * 128;
    const int jb = bid & 7;
    const int j0 = jb * 128;

    f32x4 acc[4][4] = {};
    for (int ks = 0; ks < 16; ++ks) {
        const int k0 = ks * 32;
        #pragma unroll
        for (int it = 0; it < 8; ++it) {
            int idx = it * 256 + tid;
            int m = idx >> 4, kp = idx & 15;
            float2 v = *(const float2*)(x + (m0 + m) * DD + k0 + kp * 2);
            u32 h0b, l0b, h1b, l1b;
            split2(v.x, h0b, l0b);
            split2(v.y, h1b, l1b);
            ldsA[0][m][kp] = h0b | (h1b << 16);
            ldsA[1][m][kp] = l0b | (l1b << 16);
        }
        __syncthreads();

        bf16x8 afh[4], afl[4], bfh[4], bfl[4];
        #pragma unroll
        for (int mt4 = 0; mt4 < 4; ++mt4) {
            int row = wm * 64 + mt4 * 16 + (l & 15);
            int co  = (l >> 4) * 4;
            afh[mt4] = *(const bf16x8*)&ldsA[0][row][co];
            afl[mt4] = *(const bf16x8*)&ldsA[1][row][co];
        }
        #pragma unroll
        for (int jt4 = 0; jt4 < 4; ++jt4) {
            int jtile = jb * 8 + wj * 4 + jt4;
            int off = ((jtile * 16 + ks) * 64 + l) * 8;
            bfh[jt4] = *(const bf16x8*)(WxPh + off);
            bfl[jt4] = *(const bf16x8*)(WxPl + off);
        }
        #pragma unroll
        for (int mt4 = 0; mt4 < 4; ++mt4)
            #pragma unroll
            for (int jt4 = 0; jt4 < 4; ++jt4) {
                acc[mt4][jt4] = MFMA16(afh[mt4], bfh[jt4], acc[mt4][jt4]);
                acc[mt4][jt4] = MFMA16(afh[mt4], bfl[jt4], acc[mt4][jt4]);
                acc[mt4][jt4] = MFMA16(afl[mt4], bfh[jt4], acc[mt4][jt4]);
            }
        __syncthreads();
    }
    #pragma unroll
    for (int jt4 = 0; jt4 < 4; ++jt4) {
        int j = j0 + wj * 64 + jt4 * 16 + (l & 15);
        float bj = b[j];
        #pragma unroll
        for (int mt4 = 0; mt4 < 4; ++mt4)
            #pragma unroll
            for (int r = 0; r < 4; ++r) {
                int m = m0 + wm * 64 + mt4 * 16 + (l >> 4) * 4 + r;
                out[m * HH + j] = acc[mt4][jt4][r] + bj;
            }
    }
}

// ---------------------------------------------------------------------------
// Phase 2: scan. Grid 128 x 256. Group g = bid&3 owns rows [16g,16g+16);
// block wid = bid>>2 owns cols [32wid,32wid+32); wave w owns k [256w,+256).
// flags[(g*32+wid)*4] = t+1  <=>  "h_t from block wid is at the IC".
// Wave w polls only its k-slice producers 8w..8w+7.
// ---------------------------------------------------------------------------
__global__ __launch_bounds__(256, 1) void scan_kernel(
    const u16* __restrict__ WhPh, const u16* __restrict__ WhPl,
    u16* __restrict__ hbH, u16* __restrict__ hbL,   // [2 parity][64][1024]
    float* __restrict__ out, u32* __restrict__ flags)
{
    __shared__ float ldsRed[4][16][33];

    const int tid = threadIdx.x;
    const int bid = blockIdx.x;
    const int g   = bid & 3;
    const int wid = bid >> 2;
    const int w   = tid >> 6;
    const int l   = tid & 63;

    // Wh fragments: j-tiles {2wid, 2wid+1}, k-slice [256w, 256w+256)
    bf16x8 Bh[2][8], Bl[2][8];
    #pragma unroll
    for (int jj = 0; jj < 2; ++jj)
        #pragma unroll
        for (int i = 0; i < 8; ++i) {
            int off = (((wid * 2 + jj) * 32 + w * 8 + i) * 64 + l) * 8;
            Bh[jj][i] = *(const bf16x8*)(WhPh + off);
            Bl[jj][i] = *(const bf16x8*)(WhPl + off);
        }
    // pin fragments in VGPRs: opaque touch defeats remat-from-memory
    #pragma unroll
    for (int jj = 0; jj < 2; ++jj)
        #pragma unroll
        for (int i = 0; i < 8; ++i)
            asm volatile("" : "+v"(Bh[jj][i]), "+v"(Bl[jj][i]));

    const int r  = tid >> 4, cl = tid & 15;        // this thread's output row/col
    const int nE = g * 16 + r;
    const int nA = g * 16 + (l & 15);              // A-frag batch row
    const int kbase = w * 256 + ((l >> 4) << 3);
    u32* gflags = flags + g * 128;                 // 32 flags x 16B stride

    float xw[2];
    #pragma unroll
    for (int jj = 0; jj < 2; ++jj)
        xw[jj] = out[(nE * TT) * HH + wid * 32 + jj * 16 + cl];

    for (int t = 0; t < TT; ++t) {
        const int par = t & 1;

        if (t > 0) {                               // wait for h_{t-1}
            const u32 tgt = (u32)t;
            while (true) {
                u32 fv = tgt;
                if (l < 8) fv = ld_flag(gflags + (8 * w + l) * 4);
                if (__ballot(fv >= tgt) == ~0ull) break;
            }
        }

        float xw_n[2] = {0.f, 0.f};
        if (t + 1 < TT) {
            #pragma unroll
            for (int jj = 0; jj < 2; ++jj)
                xw_n[jj] = out[(nE * TT + t + 1) * HH + wid * 32 + jj * 16 + cl];
        }

        const u16* hH = hbH + par * NN * HH + nA * HH + kbase;
        const u16* hL = hbL + par * NN * HH + nA * HH + kbase;

        u32x4 ahraw[8], alraw[8];
        #pragma unroll
        for (int i = 0; i < 8; ++i) {
            ahraw[i] = ld16_sys(hH + i * 32);
            alraw[i] = ld16_sys(hL + i * 32);
        }
        asm volatile("s_waitcnt vmcnt(0)" ::: "memory");
        __builtin_amdgcn_sched_barrier(0);

        f32x4 ahh[2] = {}, ahl[2] = {}, alh[2] = {};
        #pragma unroll
        for (int i = 0; i < 8; ++i) {
            bf16x8 Ahv = __builtin_bit_cast(bf16x8, ahraw[i]);
            bf16x8 Alv = __builtin_bit_cast(bf16x8, alraw[i]);
            #pragma unroll
            for (int jj = 0; jj < 2; ++jj) {
                ahh[jj] = MFMA16(Ahv, Bh[jj][i], ahh[jj]);
                ahl[jj] = MFMA16(Ahv, Bl[jj][i], ahl[jj]);
                alh[jj] = MFMA16(Alv, Bh[jj][i], alh[jj]);
            }
        }

        // per-wave partials -> LDS: D elem e of acc <-> row (l>>4)*4+e, col l&15
        {
            int rb = (l >> 4) * 4, cc = l & 15;
            #pragma unroll
            for (int jj = 0; jj < 2; ++jj) {
                f32x4 s4 = ahh[jj] + ahl[jj] + alh[jj];
                #pragma unroll
                for (int e = 0; e < 4; ++e)
                    ldsRed[w][rb + e][jj * 16 + cc] = s4[e];
            }
        }
        __syncthreads();

        float hv[2];
        #pragma unroll
        for (int jj = 0; jj < 2; ++jj) {
            int c2 = jj * 16 + cl;
            float s = ldsRed[0][r][c2] + ldsRed[1][r][c2]
                    + ldsRed[2][r][c2] + ldsRed[3][r][c2];
            hv[jj] = fast_tanh(xw[jj] + s);
        }

        if (t + 1 < TT) {                          // post h_t (system scope)
            #pragma unroll
            for (int jj = 0; jj < 2; ++jj) {
                u32 hi, lo; split2(hv[jj], hi, lo);
                int dst = (par ^ 1) * NN * HH + nE * HH + wid * 32 + jj * 16 + cl;
                st2_sys(hbH + dst, hi);
                st2_sys(hbL + dst, lo);
            }
        }
        #pragma unroll
        for (int jj = 0; jj < 2; ++jj)
            out[(nE * TT + t) * HH + wid * 32 + jj * 16 + cl] = hv[jj];

        if (t + 1 < TT) {
            asm volatile("s_waitcnt vmcnt(0)" ::: "memory");   // posts acked at IC
            __syncthreads();                                   // whole block acked
            if (tid == 0) st_flag(gflags + wid * 4, (u32)(t + 1));
        }
        xw[0] = xw_n[0]; xw[1] = xw_n[1];
    }
}

// ---------------------------------------------------------------------------
extern "C" void kernel_launch(void* const* d_in, const int* in_sizes, int n_in,
                              void* d_out, int out_size, void* d_ws, size_t ws_size,
                              hipStream_t stream) {
    const float* x  = (const float*)d_in[0];
    const float* h0 = (const float*)d_in[1];
    const float* Wx = (const float*)d_in[2];
    const float* Wh = (const float*)d_in[3];
    const float* b  = (const float*)d_in[4];
    float* out = (float*)d_out;

    char* ws = (char*)d_ws;
    u16* WxPh = (u16*)(ws);                           // 1 MB
    u16* WxPl = (u16*)(ws + (1u << 20));              // 1 MB
    u16* WhPh = (u16*)(ws + (2u << 20));              // 2 MB
    u16* WhPl = (u16*)(ws + (4u << 20));              // 2 MB
    u16* hbH  = (u16*)(ws + (6u << 20));              // [2][64][1024] u16 = 256 KB
    u16* hbL  = (u16*)(ws + (6u << 20) + (1u << 18)); // 256 KB
    u32* flags= (u32*)(ws + (6u << 20) + (1u << 19)); // 4 groups x 32 x 16B = 2 KB

    hipMemsetAsync(flags, 0, 4 * 32 * 4 * sizeof(u32), stream);
    prep_kernel<<<2048, 256, 0, stream>>>(Wx, Wh, h0, WxPh, WxPl, WhPh, WhPl,
                                          hbH, hbL);
    gemm_kernel<<<2048, 256, 0, stream>>>(x, b, WxPh, WxPl, out);
    scan_kernel<<<128, 256, 0, stream>>>(WhPh, WhPl, hbH, hbL, out, flags);
}

// Round 6
// 2247.993 us; speedup vs baseline: 1.0212x; 1.0212x over previous
//
#include <hip/hip_runtime.h>

// RNN: out[n,t,:] = tanh(x[n,t,:]@Wx + b + h_{t-1}@Wh),  h_{-1} = h0
// N=64, T=512, D=512, H=1024, fp32 in/out.
// Round 6: clobber-free protocol asm + in-loop "+v" pin => Wh truly
// register-resident; per-wave flags + single syncthreads/step; packed
// dword h posts; double-buffered padded ldsRed.

#define NN 64
#define TT 512
#define DD 512
#define HH 1024

typedef unsigned int  u32;
typedef unsigned short u16;

typedef __attribute__((ext_vector_type(8))) short bf16x8;
typedef __attribute__((ext_vector_type(4))) float f32x4;
typedef __attribute__((ext_vector_type(4))) u32   u32x4;

#define MFMA16(a, b, c) __builtin_amdgcn_mfma_f32_16x16x32_bf16((a), (b), (c), 0, 0, 0)

__device__ __forceinline__ u32 bf16r(float f) {          // RTNE fp32->bf16 (bits)
    u32 u = __float_as_uint(f);
    return (u + 0x7fffu + ((u >> 16) & 1u)) >> 16;
}
__device__ __forceinline__ float bf16tof(u32 h) { return __uint_as_float(h << 16); }
__device__ __forceinline__ void split2(float f, u32& hi, u32& lo) {
    hi = bf16r(f);
    lo = bf16r(f - bf16tof(hi));
}

// ---- system-scope (sc0 sc1) ops. NO "memory" clobbers: mutual ordering of
// volatile asm is what the protocol relies on; keeping clobbers out lets the
// compiler keep the (read-only) Wh fragments live in VGPRs across the loop.
__device__ __forceinline__ u32x4 ld16_sys(const u16* p) {   // issue-only
    u32x4 v;
    asm volatile("global_load_dwordx4 %0, %1, off sc0 sc1" : "=v"(v) : "v"(p));
    return v;
}
__device__ __forceinline__ void stw_sys(u32* p, u32 v) {
    asm volatile("global_store_dword %0, %1, off sc0 sc1" :: "v"(p), "v"(v));
}
__device__ __forceinline__ u32 ld_flag(const u32* p) {
    u32 v;
    asm volatile("global_load_dword %0, %1, off sc0 sc1\n\ts_waitcnt vmcnt(0)"
                 : "=v"(v) : "v"(p));
    return v;
}
__device__ __forceinline__ void wait_vm0() {
    asm volatile("s_waitcnt vmcnt(0)");
}

__device__ __forceinline__ float fast_tanh(float x) {
    float e = __expf(2.0f * x);                 // v_exp_f32 path
    return 1.0f - __fdividef(2.0f, e + 1.0f);   // exact +/-1 saturation
}

// ---------------------------------------------------------------------------
// Prep: pack Wx and Wh into MFMA-fragment order (hi/lo bf16); split h0.
// Fragment layout for 16x16x32: p = ((jt*KB + kb)*64 + lane)*8 + e
//   j = jt*16 + (lane&15),  k = kb*32 + (lane>>4)*8 + e
// ---------------------------------------------------------------------------
__global__ __launch_bounds__(256) void prep_kernel(
    const float* __restrict__ Wx, const float* __restrict__ Wh,
    const float* __restrict__ h0,
    u16* __restrict__ WxPh, u16* __restrict__ WxPl,
    u16* __restrict__ WhPh, u16* __restrict__ WhPl,
    u16* __restrict__ h0H,  u16* __restrict__ h0L)
{
    const int stride = gridDim.x * 256;
    const int gid = blockIdx.x * 256 + threadIdx.x;

    for (int p = gid; p < 64 * 16 * 64 * 8; p += stride) {   // Wx
        int e = p & 7, l = (p >> 3) & 63, kb = (p >> 9) & 15, jt = p >> 13;
        int j = jt * 16 + (l & 15);
        int k = kb * 32 + ((l >> 4) << 3) + e;
        u32 hi, lo; split2(Wx[k * HH + j], hi, lo);
        WxPh[p] = (u16)hi; WxPl[p] = (u16)lo;
    }
    for (int p = gid; p < 64 * 32 * 64 * 8; p += stride) {   // Wh
        int e = p & 7, l = (p >> 3) & 63, kb = (p >> 9) & 31, jt = p >> 14;
        int j = jt * 16 + (l & 15);
        int k = kb * 32 + ((l >> 4) << 3) + e;
        u32 hi, lo; split2(Wh[k * HH + j], hi, lo);
        WhPh[p] = (u16)hi; WhPl[p] = (u16)lo;
    }
    for (int p = gid; p < NN * HH; p += stride) {            // h0 -> parity 0
        u32 hi, lo; split2(h0[p], hi, lo);
        h0H[p] = (u16)hi; h0L[p] = (u16)lo;
    }
}

// ---------------------------------------------------------------------------
// Phase 1: out = x@Wx + b   (split-bf16, 128x128 tiles, grid 2048)
// ---------------------------------------------------------------------------
__global__ __launch_bounds__(256) void gemm_kernel(
    const float* __restrict__ x, const float* __restrict__ b,
    const u16* __restrict__ WxPh, const u16* __restrict__ WxPl,
    float* __restrict__ out)
{
    __shared__ __align__(16) u32 ldsA[2][128][20];

    const int tid = threadIdx.x;
    const int bid = blockIdx.x;
    const int w   = tid >> 6;
    const int l   = tid & 63;
    const int wm = w >> 1, wj = w & 1;

    const int m0 = (bid >> 3) * 128;
    const int jb = bid & 7;
    const int j0 = jb * 128;

    f32x4 acc[4][4] = {};
    for (int ks = 0; ks < 16; ++ks) {
        const int k0 = ks * 32;
        #pragma unroll
        for (int it = 0; it < 8; ++it) {
            int idx = it * 256 + tid;
            int m = idx >> 4, kp = idx & 15;
            float2 v = *(const float2*)(x + (m0 + m) * DD + k0 + kp * 2);
            u32 h0b, l0b, h1b, l1b;
            split2(v.x, h0b, l0b);
            split2(v.y, h1b, l1b);
            ldsA[0][m][kp] = h0b | (h1b << 16);
            ldsA[1][m][kp] = l0b | (l1b << 16);
        }
        __syncthreads();

        bf16x8 afh[4], afl[4], bfh[4], bfl[4];
        #pragma unroll
        for (int mt4 = 0; mt4 < 4; ++mt4) {
            int row = wm * 64 + mt4 * 16 + (l & 15);
            int co  = (l >> 4) * 4;
            afh[mt4] = *(const bf16x8*)&ldsA[0][row][co];
            afl[mt4] = *(const bf16x8*)&ldsA[1][row][co];
        }
        #pragma unroll
        for (int jt4 = 0; jt4 < 4; ++jt4) {
            int jtile = jb * 8 + wj * 4 + jt4;
            int off = ((jtile * 16 + ks) * 64 + l) * 8;
            bfh[jt4] = *(const bf16x8*)(WxPh + off);
            bfl[jt4] = *(const bf16x8*)(WxPl + off);
        }
        #pragma unroll
        for (int mt4 = 0; mt4 < 4; ++mt4)
            #pragma unroll
            for (int jt4 = 0; jt4 < 4; ++jt4) {
                acc[mt4][jt4] = MFMA16(afh[mt4], bfh[jt4], acc[mt4][jt4]);
                acc[mt4][jt4] = MFMA16(afh[mt4], bfl[jt4], acc[mt4][jt4]);
                acc[mt4][jt4] = MFMA16(afl[mt4], bfh[jt4], acc[mt4][jt4]);
            }
        __syncthreads();
    }
    #pragma unroll
    for (int jt4 = 0; jt4 < 4; ++jt4) {
        int j = j0 + wj * 64 + jt4 * 16 + (l & 15);
        float bj = b[j];
        #pragma unroll
        for (int mt4 = 0; mt4 < 4; ++mt4)
            #pragma unroll
            for (int r = 0; r < 4; ++r) {
                int m = m0 + wm * 64 + mt4 * 16 + (l >> 4) * 4 + r;
                out[m * HH + j] = acc[mt4][jt4][r] + bj;
            }
    }
}

// ---------------------------------------------------------------------------
// Phase 2: scan. Grid 128 x 256. Group g = bid&3 owns rows [16g,16g+16);
// block wid = bid>>2 owns cols [32wid,32wid+32); wave w owns k [256w,+256).
// Per-wave flags: flags[g*128 + wid*4 + wv] = t+1 <=> wave wv of block wid
// posted its 4 rows of h_t. Consumer wave w polls its 8 producer blocks'
// 4 wave-flags each (32 lanes, 1 flag/lane). One __syncthreads per step
// (ldsRed double-buffered; WAR safe through the t-1 barrier).
// ---------------------------------------------------------------------------
__global__ __launch_bounds__(256, 1) void scan_kernel(
    const u16* __restrict__ WhPh, const u16* __restrict__ WhPl,
    u16* __restrict__ hbH, u16* __restrict__ hbL,   // [2 parity][64][1024]
    float* __restrict__ out, u32* __restrict__ flags)
{
    __shared__ float ldsRed[2][4][16][34];

    const int tid = threadIdx.x;
    const int bid = blockIdx.x;
    const int g   = bid & 3;
    const int wid = bid >> 2;
    const int w   = tid >> 6;
    const int l   = tid & 63;
    const int lr  = l >> 4;          // 0..3
    const int cc  = l & 15;

    // Wh fragments: j-tiles {2wid, 2wid+1}, k-slice [256w, 256w+256)
    bf16x8 Bh[2][8], Bl[2][8];
    #pragma unroll
    for (int jj = 0; jj < 2; ++jj)
        #pragma unroll
        for (int i = 0; i < 8; ++i) {
            int off = (((wid * 2 + jj) * 32 + w * 8 + i) * 64 + l) * 8;
            Bh[jj][i] = *(const bf16x8*)(WhPh + off);
            Bl[jj][i] = *(const bf16x8*)(WhPl + off);
        }

    const int nA    = g * 16 + cc;             // A-frag batch row
    const int kbase = w * 256 + lr * 8;

    const int rF = 4 * w + lr;                 // row this thread finalizes
    const int nF = g * 16 + rF;
    const int c0 = 2 * cc;                     // col pair base (within 32)

    u32* gflags = flags + g * 128;             // [32 blocks][4 waves]
    const u32* pollp = gflags + 32 * w + l;    // lane l (<32): block 8w+(l>>2), wave l&3

    float2 xw = *(const float2*)&out[(nF * TT) * HH + wid * 32 + c0];

    for (int t = 0; t < TT; ++t) {
        const int par = t & 1;

        // pin Wh fragments: "+v" makes them loop-carried register state
        // (not rematerializable from memory by the allocator).
        #pragma unroll
        for (int jj = 0; jj < 2; ++jj) {
            asm volatile("" : "+v"(Bh[jj][0]), "+v"(Bh[jj][1]), "+v"(Bh[jj][2]),
                              "+v"(Bh[jj][3]), "+v"(Bh[jj][4]), "+v"(Bh[jj][5]),
                              "+v"(Bh[jj][6]), "+v"(Bh[jj][7]));
            asm volatile("" : "+v"(Bl[jj][0]), "+v"(Bl[jj][1]), "+v"(Bl[jj][2]),
                              "+v"(Bl[jj][3]), "+v"(Bl[jj][4]), "+v"(Bl[jj][5]),
                              "+v"(Bl[jj][6]), "+v"(Bl[jj][7]));
        }

        if (t > 0) {                           // wait for h_{t-1} (my k-slice)
            const u32 tgt = (u32)t;
            while (true) {
                u32 fv = tgt;
                if (l < 32) fv = ld_flag(pollp);
                if (__ballot(fv >= tgt) == ~0ull) break;
            }
        }

        float2 xw_n = make_float2(0.f, 0.f);
        if (t + 1 < TT)
            xw_n = *(const float2*)&out[(nF * TT + t + 1) * HH + wid * 32 + c0];

        const u16* hH = hbH + par * NN * HH + nA * HH + kbase;
        const u16* hL = hbL + par * NN * HH + nA * HH + kbase;

        u32x4 ahraw[8], alraw[8];
        #pragma unroll
        for (int i = 0; i < 8; ++i) {
            ahraw[i] = ld16_sys(hH + i * 32);
            alraw[i] = ld16_sys(hL + i * 32);
        }
        wait_vm0();
        __builtin_amdgcn_sched_barrier(0);

        f32x4 ahh[2] = {}, ahl[2] = {}, alh[2] = {};
        #pragma unroll
        for (int i = 0; i < 8; ++i) {
            bf16x8 Ahv = __builtin_bit_cast(bf16x8, ahraw[i]);
            bf16x8 Alv = __builtin_bit_cast(bf16x8, alraw[i]);
            #pragma unroll
            for (int jj = 0; jj < 2; ++jj) {
                ahh[jj] = MFMA16(Ahv, Bh[jj][i], ahh[jj]);
                ahl[jj] = MFMA16(Ahv, Bl[jj][i], ahl[jj]);
                alh[jj] = MFMA16(Alv, Bh[jj][i], alh[jj]);
            }
        }

        // per-wave partials -> LDS[par]: C elem e <-> row lr*4+e, col jj*16+cc
        #pragma unroll
        for (int jj = 0; jj < 2; ++jj) {
            f32x4 s4 = ahh[jj] + ahl[jj] + alh[jj];
            #pragma unroll
            for (int e = 0; e < 4; ++e)
                ldsRed[par][w][lr * 4 + e][jj * 16 + cc] = s4[e];
        }
        __syncthreads();

        float sx = 0.f, sy = 0.f;
        #pragma unroll
        for (int wq = 0; wq < 4; ++wq) {
            float2 v = *(const float2*)&ldsRed[par][wq][rF][c0];
            sx += v.x; sy += v.y;
        }
        float hv0 = fast_tanh(xw.x + sx);
        float hv1 = fast_tanh(xw.y + sy);

        *(float2*)&out[(nF * TT + t) * HH + wid * 32 + c0] = make_float2(hv0, hv1);

        if (t + 1 < TT) {                      // post h_t (system scope)
            u32 h0b, l0b, h1b, l1b;
            split2(hv0, h0b, l0b);
            split2(hv1, h1b, l1b);
            int dst = (par ^ 1) * NN * HH + nF * HH + wid * 32 + c0;   // even
            stw_sys((u32*)(hbH + dst), h0b | (h1b << 16));
            stw_sys((u32*)(hbL + dst), l0b | (l1b << 16));
            wait_vm0();                        // this wave's posts acked at IC
            if (l == 0)
                asm volatile("global_store_dword %0, %1, off sc0 sc1"
                             :: "v"(gflags + wid * 4 + w), "v"((u32)(t + 1)));
        }
        xw = xw_n;
    }
}

// ---------------------------------------------------------------------------
extern "C" void kernel_launch(void* const* d_in, const int* in_sizes, int n_in,
                              void* d_out, int out_size, void* d_ws, size_t ws_size,
                              hipStream_t stream) {
    const float* x  = (const float*)d_in[0];
    const float* h0 = (const float*)d_in[1];
    const float* Wx = (const float*)d_in[2];
    const float* Wh = (const float*)d_in[3];
    const float* b  = (const float*)d_in[4];
    float* out = (float*)d_out;

    char* ws = (char*)d_ws;
    u16* WxPh = (u16*)(ws);                           // 1 MB
    u16* WxPl = (u16*)(ws + (1u << 20));              // 1 MB
    u16* WhPh = (u16*)(ws + (2u << 20));              // 2 MB
    u16* WhPl = (u16*)(ws + (4u << 20));              // 2 MB
    u16* hbH  = (u16*)(ws + (6u << 20));              // [2][64][1024] u16 = 256 KB
    u16* hbL  = (u16*)(ws + (6u << 20) + (1u << 18)); // 256 KB
    u32* flags= (u32*)(ws + (6u << 20) + (1u << 19)); // 4 groups x 128 u32 = 2 KB

    hipMemsetAsync(flags, 0, 4 * 128 * sizeof(u32), stream);
    prep_kernel<<<2048, 256, 0, stream>>>(Wx, Wh, h0, WxPh, WxPl, WhPh, WhPl,
                                          hbH, hbL);
    gemm_kernel<<<2048, 256, 0, stream>>>(x, b, WxPh, WxPl, out);
    scan_kernel<<<128, 256, 0, stream>>>(WhPh, WhPl, hbH, hbL, out, flags);
}